// Round 2
// baseline (342.705 us; speedup 1.0000x reference)
//
#include <hip/hip_runtime.h>
#include <math.h>

// Problem constants
#define NN 512
#define DD 512
#define NPAIRS 130816            // 512*511/2
#define TYPES_OFF 0              // [P,10] floats
#define ARGMAX_OFF 1308160      // [P] floats
#define STRENGTH_OFF 1438976    // [P] floats

// ws layout (byte offsets):
//   ca_d  double[512][512]  @ 0          (cb1 + features@cw1[:D], fp64)
//   cb_d  double[512][512]  @ 2097152    (features@cw1[D:],       fp64)
//   sa_f  float [512][256]  @ 4194304    (sb1 + features@sw1[:D], fp32)
//   sb_f  float [512][256]  @ 4718592    (features@sw1[D:],       fp32)
//   cw2d  double[512][10]   @ 5242880
// total 5,283,840 bytes

__global__ void cvt_cw2_kernel(const float* __restrict__ cw2, double* __restrict__ cw2d) {
    int i = blockIdx.x * 256 + threadIdx.x;
    if (i < 5120) cw2d[i] = (double)cw2[i];
}

// init: ca_d rows = cb1 (bias folded), cb_d = 0; sa_f rows = sb1, sb_f = 0.
__global__ __launch_bounds__(256) void init_ws_kernel(
    const float* __restrict__ cb1, const float* __restrict__ sb1,
    double* __restrict__ ca_d, double* __restrict__ cb_d,
    float* __restrict__ sa_f, float* __restrict__ sb_f)
{
    int idx = blockIdx.x * 256 + threadIdx.x;      // grid 1024 -> 262144
    ca_d[idx] = (double)cb1[idx & 511];
    cb_d[idx] = 0.0;
    if (idx < 131072) {
        sa_f[idx] = sb1[idx & 255];
        sb_f[idx] = 0.f;
    }
}

// fp64 proj: out[512,1024] += F @ [cw1[:512] | cw1[512:]], K-split 2 (z), atomicAdd.
__global__ __launch_bounds__(256, 4) void proj_c_kernel(
    const float* __restrict__ F, const float* __restrict__ cw1,
    double* __restrict__ ca_d, double* __restrict__ cb_d)
{
    __shared__ double As[32 * 34];   // [k][m]
    __shared__ double Bs[32 * 34];   // [k][n]

    const int t = threadIdx.x;
    const int m0 = blockIdx.y * 32;
    const int n0 = blockIdx.x * 32;
    const int z  = blockIdx.z;       // K half

    const float* Bp; double* outp; int coloff;
    if (n0 < 512) { Bp = cw1;             outp = ca_d; coloff = n0; }
    else          { Bp = cw1 + 512 * 512; outp = cb_d; coloff = n0 - 512; }

    const int ar  = t >> 3;
    const int akq = t & 7;
    const int ty  = t >> 4;
    const int tx  = t & 15;

    double acc00 = 0, acc01 = 0, acc10 = 0, acc11 = 0;

    for (int k0 = z * 256; k0 < z * 256 + 256; k0 += 32) {
        float4 fa = *(const float4*)&F [(m0 + ar) * 512 + k0 + akq * 4];
        float4 fb = *(const float4*)&Bp[(k0 + ar) * 512 + coloff + akq * 4];
        __syncthreads();
        As[(akq * 4 + 0) * 34 + ar] = (double)fa.x;
        As[(akq * 4 + 1) * 34 + ar] = (double)fa.y;
        As[(akq * 4 + 2) * 34 + ar] = (double)fa.z;
        As[(akq * 4 + 3) * 34 + ar] = (double)fa.w;
        double2* bd = (double2*)&Bs[ar * 34 + akq * 4];
        bd[0] = make_double2((double)fb.x, (double)fb.y);
        bd[1] = make_double2((double)fb.z, (double)fb.w);
        __syncthreads();
        #pragma unroll
        for (int kk = 0; kk < 32; ++kk) {
            double2 av = *(double2*)&As[kk * 34 + ty * 2];
            double2 bv = *(double2*)&Bs[kk * 34 + tx * 2];
            acc00 = fma(av.x, bv.x, acc00);
            acc01 = fma(av.x, bv.y, acc01);
            acc10 = fma(av.y, bv.x, acc10);
            acc11 = fma(av.y, bv.y, acc11);
        }
    }

    const int m = m0 + ty * 2;
    const int c = coloff + tx * 2;
    unsafeAtomicAdd(&outp[(m + 0) * 512 + c + 0], acc00);
    unsafeAtomicAdd(&outp[(m + 0) * 512 + c + 1], acc01);
    unsafeAtomicAdd(&outp[(m + 1) * 512 + c + 0], acc10);
    unsafeAtomicAdd(&outp[(m + 1) * 512 + c + 1], acc11);
}

// fp32 proj: out[512,512] += F @ [sw1[:512] | sw1[512:]], ldb=256, K-split 4.
__global__ __launch_bounds__(256, 4) void proj_s_kernel(
    const float* __restrict__ F, const float* __restrict__ sw1,
    float* __restrict__ sa_f, float* __restrict__ sb_f)
{
    __shared__ float As[32 * 36];
    __shared__ float Bs[32 * 36];

    const int t = threadIdx.x;
    const int m0 = blockIdx.y * 32;
    const int n0 = blockIdx.x * 32;
    const int z  = blockIdx.z;       // K quarter

    const float* Bp; float* outp; int coloff;
    if (n0 < 256) { Bp = sw1;             outp = sa_f; coloff = n0; }
    else          { Bp = sw1 + 512 * 256; outp = sb_f; coloff = n0 - 256; }

    const int ar  = t >> 3;
    const int akq = t & 7;
    const int ty  = t >> 4;
    const int tx  = t & 15;

    float acc00 = 0.f, acc01 = 0.f, acc10 = 0.f, acc11 = 0.f;

    for (int k0 = z * 128; k0 < z * 128 + 128; k0 += 32) {
        float4 fa = *(const float4*)&F [(m0 + ar) * 512 + k0 + akq * 4];
        float4 fb = *(const float4*)&Bp[(k0 + ar) * 256 + coloff + akq * 4];
        __syncthreads();
        As[(akq * 4 + 0) * 36 + ar] = fa.x;
        As[(akq * 4 + 1) * 36 + ar] = fa.y;
        As[(akq * 4 + 2) * 36 + ar] = fa.z;
        As[(akq * 4 + 3) * 36 + ar] = fa.w;
        *(float4*)&Bs[ar * 36 + akq * 4] = fb;
        __syncthreads();
        #pragma unroll
        for (int kk = 0; kk < 32; ++kk) {
            float2 av = *(float2*)&As[kk * 36 + ty * 2];
            float2 bv = *(float2*)&Bs[kk * 36 + tx * 2];
            acc00 = fmaf(av.x, bv.x, acc00);
            acc01 = fmaf(av.x, bv.y, acc01);
            acc10 = fmaf(av.y, bv.x, acc10);
            acc11 = fmaf(av.y, bv.y, acc11);
        }
    }

    const int m = m0 + ty * 2;
    const int c = coloff + tx * 2;
    unsafeAtomicAdd(&outp[(m + 0) * 256 + c + 0], acc00);
    unsafeAtomicAdd(&outp[(m + 0) * 256 + c + 1], acc01);
    unsafeAtomicAdd(&outp[(m + 1) * 256 + c + 0], acc10);
    unsafeAtomicAdd(&outp[(m + 1) * 256 + c + 1], acc11);
}

// Pair phase: block = 8x8 pair tile, 4 waves = 4 K-quarters, LDS combine.
// Grid: 2080 triangular tiles (64x64 tile space, bj >= bi).
__global__ __launch_bounds__(256, 8) void pair_kernel(
    const double* __restrict__ ca_d, const double* __restrict__ cb_d,
    const float* __restrict__ sa_f, const float* __restrict__ sb_f,
    const double* __restrict__ cw2d, const float* __restrict__ cb2,
    const float* __restrict__ sw2, const float* __restrict__ sb2,
    float* __restrict__ out)
{
    // triangular tile decode: S(bi) = bi*(129-bi)/2
    const int b = blockIdx.x;
    int bi = (int)floorf((129.0f - sqrtf(16641.0f - 8.0f * (float)b)) * 0.5f);
    while ((bi + 1) * (129 - (bi + 1)) / 2 <= b) ++bi;
    while (bi * (129 - bi) / 2 > b) --bi;
    const int bj = bi + (b - bi * (129 - bi) / 2);
    const int i0 = bi * 8, j0 = bj * 8;

    const int t = threadIdx.x;
    const int q = t >> 6;            // K-quarter = wave id
    const int l = t & 63;
    const int pi = l >> 3, pj = l & 7;
    const int i = i0 + pi, j = j0 + pj;

    __shared__ double smem_d[2176];                 // 17408 B
    double* sA  = smem_d;                           // [4*8][34]
    double* sB  = smem_d + 1088;
    float*  sSa = (float*)smem_d;                   // [4*8][68]
    float*  sSb = (float*)smem_d + 2176;
    double* lgbuf = smem_d;                         // [3][64][10]
    float*  stbuf = (float*)(smem_d + 1920);        // [3][64]

    // ---------------- strength (fp32), K=64 per quarter ----------------
    // stage sSa/sSb: 1024 float4, 4 per thread
    #pragma unroll
    for (int u = 0; u < 4; ++u) {
        int idx = u * 256 + t;
        int kq  = idx & 15;
        int row = (idx >> 4) & 7;
        int qq  = (idx >> 7) & 3;
        int arr = idx >> 9;
        const float* src = arr ? (sb_f + (j0 + row) * 256) : (sa_f + (i0 + row) * 256);
        float4 v = *(const float4*)(src + qq * 64 + kq * 4);
        float* dst = (arr ? sSb : sSa) + (qq * 8 + row) * 68 + kq * 4;
        *(float4*)dst = v;
    }
    __syncthreads();
    float accs = 0.f;
    {
        const float* sw2q = sw2 + q * 64;
        const float* ra = sSa + (q * 8 + pi) * 68;
        const float* rb = sSb + (q * 8 + pj) * 68;
        #pragma unroll 16
        for (int kk = 0; kk < 64; ++kk) {
            float h = fmaxf(ra[kk] + rb[kk], 0.f);
            accs = fmaf(h, sw2q[kk], accs);
        }
    }

    // ---------------- classifier (fp64), K=128 per quarter ----------------
    double lg[10];
    #pragma unroll
    for (int c = 0; c < 10; ++c) lg[c] = 0.0;
    const double* wq = cw2d + q * 128 * 10;

    for (int c4 = 0; c4 < 4; ++c4) {
        // stage: 1024 double2, 4 per thread (prefetch before barrier)
        double2 v[4];
        int off[4], arr4[4];
        #pragma unroll
        for (int u = 0; u < 4; ++u) {
            int idx = u * 256 + t;
            int kq  = idx & 15;
            int row = (idx >> 4) & 7;
            int qq  = (idx >> 7) & 3;
            int arr = idx >> 9;
            const double* src = arr ? (cb_d + (j0 + row) * 512) : (ca_d + (i0 + row) * 512);
            v[u] = *(const double2*)(src + qq * 128 + c4 * 32 + kq * 2);
            off[u] = (qq * 8 + row) * 34 + kq * 2;
            arr4[u] = arr;
        }
        __syncthreads();   // prior reads of sA/sB (or sSa/sSb) done
        #pragma unroll
        for (int u = 0; u < 4; ++u) {
            double* dst = (arr4[u] ? sB : sA) + off[u];
            *(double2*)dst = v[u];
        }
        __syncthreads();
        const double* ra = sA + (q * 8 + pi) * 34;
        const double* rb = sB + (q * 8 + pj) * 34;
        const double* wc = wq + c4 * 32 * 10;
        #pragma unroll 8
        for (int kk = 0; kk < 32; ++kk) {
            double h = fmax(ra[kk] + rb[kk], 0.0);
            const double* w = wc + kk * 10;
            #pragma unroll
            for (int c = 0; c < 10; ++c) lg[c] = fma(h, w[c], lg[c]);
        }
    }

    // ---------------- combine via LDS ----------------
    __syncthreads();
    if (q > 0) {
        double* dst = lgbuf + ((q - 1) * 64 + l) * 10;
        #pragma unroll
        for (int c = 0; c < 10; ++c) dst[c] = lg[c];
        stbuf[(q - 1) * 64 + l] = accs;
    }
    __syncthreads();
    if (q == 0) {
        #pragma unroll
        for (int w = 0; w < 3; ++w) {
            const double* srcb = lgbuf + (w * 64 + l) * 10;
            #pragma unroll
            for (int c = 0; c < 10; ++c) lg[c] += srcb[c];
        }
        float st = accs + stbuf[l] + stbuf[64 + l] + stbuf[128 + l] + sb2[0];

        #pragma unroll
        for (int c = 0; c < 10; ++c) lg[c] += (double)cb2[c];
        double mx = lg[0]; int am = 0;
        #pragma unroll
        for (int c = 1; c < 10; ++c) {
            if (lg[c] > mx) { mx = lg[c]; am = c; }   // first-max == np.argmax
        }
        float tf[10]; float s = 0.f;
        #pragma unroll
        for (int c = 0; c < 10; ++c) { tf[c] = (float)(lg[c] - mx); s += __expf(tf[c]); }
        float ls = __logf(s);

        if (j > i) {
            const int p = i * 511 - (i * (i - 1)) / 2 + (j - i - 1);
            float* tp = out + TYPES_OFF + p * 10;
            #pragma unroll
            for (int c = 0; c < 10; ++c) tp[c] = tf[c] - ls;
            out[ARGMAX_OFF + p] = (float)am;
            out[STRENGTH_OFF + p] = 1.0f / (1.0f + __expf(-st));
        }
    }
}

extern "C" void kernel_launch(void* const* d_in, const int* in_sizes, int n_in,
                              void* d_out, int out_size, void* d_ws, size_t ws_size,
                              hipStream_t stream) {
    const float* F   = (const float*)d_in[0];
    const float* cw1 = (const float*)d_in[1];
    const float* cb1 = (const float*)d_in[2];
    const float* cw2 = (const float*)d_in[3];
    const float* cb2 = (const float*)d_in[4];
    const float* sw1 = (const float*)d_in[5];
    const float* sb1 = (const float*)d_in[6];
    const float* sw2 = (const float*)d_in[7];
    const float* sb2 = (const float*)d_in[8];
    float* out = (float*)d_out;

    char* ws = (char*)d_ws;
    double* ca_d = (double*)(ws);
    double* cb_d = (double*)(ws + 2097152);
    float*  sa_f = (float*)(ws + 4194304);
    float*  sb_f = (float*)(ws + 4718592);
    double* cw2d = (double*)(ws + 5242880);

    hipLaunchKernelGGL(cvt_cw2_kernel, dim3(20), dim3(256), 0, stream, cw2, cw2d);
    hipLaunchKernelGGL(init_ws_kernel, dim3(1024), dim3(256), 0, stream,
                       cb1, sb1, ca_d, cb_d, sa_f, sb_f);
    hipLaunchKernelGGL(proj_c_kernel, dim3(32, 16, 2), dim3(256), 0, stream, F, cw1, ca_d, cb_d);
    hipLaunchKernelGGL(proj_s_kernel, dim3(16, 16, 4), dim3(256), 0, stream, F, sw1, sa_f, sb_f);
    hipLaunchKernelGGL(pair_kernel, dim3(2080), dim3(256), 0, stream,
                       ca_d, cb_d, sa_f, sb_f, cw2d, cb2, sw2, sb2, out);
}

// Round 3
// 163.993 us; speedup vs baseline: 2.0898x; 2.0898x over previous
//
#include <hip/hip_runtime.h>
#include <math.h>

// Problem constants
#define NN 512
#define DD 512
#define NPAIRS 130816            // 512*511/2
#define TYPES_OFF 0              // [P,10] floats
#define ARGMAX_OFF 1308160      // [P] floats
#define STRENGTH_OFF 1438976    // [P] floats

// ws layout (byte offsets):
//   ca_d  double[512][512]  @ 0          (cb1 + features@cw1[:D], fp64)
//   cb_d  double[512][512]  @ 2097152    (features@cw1[D:],       fp64)
//   sa_f  float [512][256]  @ 4194304    (sb1 + features@sw1[:D], fp32)
//   sb_f  float [512][256]  @ 4718592    (features@sw1[D:],       fp32)
//   cw2d  double[512][10]   @ 5242880
// total 5,283,840 bytes

// init: ca_d rows = cb1 (bias folded), cb_d = 0; sa_f rows = sb1, sb_f = 0; cw2 -> fp64.
__global__ __launch_bounds__(256) void init_ws_kernel(
    const float* __restrict__ cb1, const float* __restrict__ sb1,
    const float* __restrict__ cw2,
    double* __restrict__ ca_d, double* __restrict__ cb_d,
    float* __restrict__ sa_f, float* __restrict__ sb_f,
    double* __restrict__ cw2d)
{
    int idx = blockIdx.x * 256 + threadIdx.x;      // grid 1024 -> 262144
    ca_d[idx] = (double)cb1[idx & 511];
    cb_d[idx] = 0.0;
    if (idx < 131072) {
        sa_f[idx] = sb1[idx & 255];
        sb_f[idx] = 0.f;
    }
    if (idx < 5120) cw2d[idx] = (double)cw2[idx];
}

// Fused projections. Blocks [0,256): fp64 classifier proj (64x64 tile, K-split 2).
//                   Blocks [256,384): fp32 strength proj  (64x64 tile, K-split 2).
// 4x4 micro-tile per thread; partials combined with unsafeAtomicAdd.
__global__ __launch_bounds__(256, 4) void proj_kernel(
    const float* __restrict__ F, const float* __restrict__ cw1,
    const float* __restrict__ sw1,
    double* __restrict__ ca_d, double* __restrict__ cb_d,
    float* __restrict__ sa_f, float* __restrict__ sb_f)
{
    __shared__ double sh[2 * 16 * 66];   // 16896 B, overlaid by fp32 branch

    const int t = threadIdx.x;
    const int b = blockIdx.x;

    const int am = t & 63, aq = t >> 6;   // A staging: row, k-quad
    const int br = t >> 4, bq = t & 15;   // B staging: k-row, col-quad
    const int ty = t >> 4, tx = t & 15;   // compute: 4-row group, 4-col group

    if (b < 256) {
        // ---------------- fp64 classifier projection ----------------
        const int z  = b >> 7;           // K half: [z*256, z*256+256)
        const int r  = b & 127;
        const int m0 = (r >> 4) * 64;
        const int ng = (r & 15) * 64;    // 0..960 over 1024 cols
        const float* Bp  = (ng < 512) ? cw1 : cw1 + 512 * 512;
        double* outp     = (ng < 512) ? ca_d : cb_d;
        const int coloff = (ng < 512) ? ng : ng - 512;

        double* As = sh;                 // [16][66], [k][m]
        double* Bs = sh + 16 * 66;       // [16][66], [k][n]

        double acc[4][4];
        #pragma unroll
        for (int r2 = 0; r2 < 4; ++r2)
            #pragma unroll
            for (int c2 = 0; c2 < 4; ++c2) acc[r2][c2] = 0.0;

        for (int k0 = z * 256; k0 < z * 256 + 256; k0 += 16) {
            float4 fa = *(const float4*)&F [(m0 + am) * 512 + k0 + aq * 4];
            float4 fb = *(const float4*)&Bp[(k0 + br) * 512 + coloff + bq * 4];
            __syncthreads();
            As[(aq * 4 + 0) * 66 + am] = (double)fa.x;
            As[(aq * 4 + 1) * 66 + am] = (double)fa.y;
            As[(aq * 4 + 2) * 66 + am] = (double)fa.z;
            As[(aq * 4 + 3) * 66 + am] = (double)fa.w;
            double2* bd = (double2*)&Bs[br * 66 + bq * 4];
            bd[0] = make_double2((double)fb.x, (double)fb.y);
            bd[1] = make_double2((double)fb.z, (double)fb.w);
            __syncthreads();
            #pragma unroll
            for (int kk = 0; kk < 16; ++kk) {
                double2 a0 = *(double2*)&As[kk * 66 + ty * 4];
                double2 a1 = *(double2*)&As[kk * 66 + ty * 4 + 2];
                double2 b0 = *(double2*)&Bs[kk * 66 + tx * 4];
                double2 b1 = *(double2*)&Bs[kk * 66 + tx * 4 + 2];
                double av[4] = {a0.x, a0.y, a1.x, a1.y};
                double bv[4] = {b0.x, b0.y, b1.x, b1.y};
                #pragma unroll
                for (int r2 = 0; r2 < 4; ++r2)
                    #pragma unroll
                    for (int c2 = 0; c2 < 4; ++c2)
                        acc[r2][c2] = fma(av[r2], bv[c2], acc[r2][c2]);
            }
        }
        #pragma unroll
        for (int r2 = 0; r2 < 4; ++r2)
            #pragma unroll
            for (int c2 = 0; c2 < 4; ++c2)
                unsafeAtomicAdd(&outp[(m0 + ty * 4 + r2) * 512 + coloff + tx * 4 + c2],
                                acc[r2][c2]);
    } else {
        // ---------------- fp32 strength projection ----------------
        const int b2 = b - 256;
        const int z  = b2 >> 6;          // K half
        const int r  = b2 & 63;
        const int m0 = (r >> 3) * 64;
        const int ng = (r & 7) * 64;     // 0..448 over 512 cols
        const float* Bp  = (ng < 256) ? sw1 : sw1 + 512 * 256;
        float* outp      = (ng < 256) ? sa_f : sb_f;
        const int coloff = (ng < 256) ? ng : ng - 256;

        float* Asf = (float*)sh;         // [16][68]
        float* Bsf = (float*)sh + 16 * 68;

        float acc[4][4];
        #pragma unroll
        for (int r2 = 0; r2 < 4; ++r2)
            #pragma unroll
            for (int c2 = 0; c2 < 4; ++c2) acc[r2][c2] = 0.f;

        for (int k0 = z * 256; k0 < z * 256 + 256; k0 += 16) {
            float4 fa = *(const float4*)&F [(m0 + am) * 512 + k0 + aq * 4];
            float4 fb = *(const float4*)&Bp[(k0 + br) * 256 + coloff + bq * 4];
            __syncthreads();
            Asf[(aq * 4 + 0) * 68 + am] = fa.x;
            Asf[(aq * 4 + 1) * 68 + am] = fa.y;
            Asf[(aq * 4 + 2) * 68 + am] = fa.z;
            Asf[(aq * 4 + 3) * 68 + am] = fa.w;
            *(float4*)&Bsf[br * 68 + bq * 4] = fb;   // 68*4 B stride keeps 16B align
            __syncthreads();
            #pragma unroll
            for (int kk = 0; kk < 16; ++kk) {
                float4 a4 = *(float4*)&Asf[kk * 68 + ty * 4];
                float4 b4 = *(float4*)&Bsf[kk * 68 + tx * 4];
                float av[4] = {a4.x, a4.y, a4.z, a4.w};
                float bv[4] = {b4.x, b4.y, b4.z, b4.w};
                #pragma unroll
                for (int r2 = 0; r2 < 4; ++r2)
                    #pragma unroll
                    for (int c2 = 0; c2 < 4; ++c2)
                        acc[r2][c2] = fmaf(av[r2], bv[c2], acc[r2][c2]);
            }
        }
        #pragma unroll
        for (int r2 = 0; r2 < 4; ++r2)
            #pragma unroll
            for (int c2 = 0; c2 < 4; ++c2)
                unsafeAtomicAdd(&outp[(m0 + ty * 4 + r2) * 256 + coloff + tx * 4 + c2],
                                acc[r2][c2]);
    }
}

// Pair phase: block = 8x8 pair tile, 4 waves = 4 K-quarters, LDS combine.
// Grid: 2080 triangular tiles (64x64 tile space, bj >= bi).
// launch_bounds (256,4): 128-VGPR cap -> no spills (R2's (256,8) spilled lg[] to scratch).
__global__ __launch_bounds__(256, 4) void pair_kernel(
    const double* __restrict__ ca_d, const double* __restrict__ cb_d,
    const float* __restrict__ sa_f, const float* __restrict__ sb_f,
    const double* __restrict__ cw2d, const float* __restrict__ cb2,
    const float* __restrict__ sw2, const float* __restrict__ sb2,
    float* __restrict__ out)
{
    // triangular tile decode: S(bi) = bi*(129-bi)/2
    const int b = blockIdx.x;
    int bi = (int)floorf((129.0f - sqrtf(16641.0f - 8.0f * (float)b)) * 0.5f);
    while ((bi + 1) * (129 - (bi + 1)) / 2 <= b) ++bi;
    while (bi * (129 - bi) / 2 > b) --bi;
    const int bj = bi + (b - bi * (129 - bi) / 2);
    const int i0 = bi * 8, j0 = bj * 8;

    const int t = threadIdx.x;
    const int q  = t >> 6;                               // K-quarter = wave id
    const int qu = __builtin_amdgcn_readfirstlane(q);    // wave-uniform -> s_load bases
    const int l = t & 63;
    const int pi = l >> 3, pj = l & 7;
    const int i = i0 + pi, j = j0 + pj;

    __shared__ double smem_d[2176];                 // 17408 B
    double* sA  = smem_d;                           // [4*8][34]
    double* sB  = smem_d + 1088;
    float*  sSa = (float*)smem_d;                   // [4*8][68]
    float*  sSb = (float*)smem_d + 2176;
    double* lgbuf = smem_d;                         // [3][64][10]
    float*  stbuf = (float*)(smem_d + 1920);        // [3][64]

    // ---------------- strength (fp32), K=64 per quarter ----------------
    #pragma unroll
    for (int u = 0; u < 4; ++u) {
        int idx = u * 256 + t;
        int kq  = idx & 15;
        int row = (idx >> 4) & 7;
        int qq  = (idx >> 7) & 3;
        int arr = idx >> 9;
        const float* src = arr ? (sb_f + (j0 + row) * 256) : (sa_f + (i0 + row) * 256);
        float4 v = *(const float4*)(src + qq * 64 + kq * 4);
        float* dst = (arr ? sSb : sSa) + (qq * 8 + row) * 68 + kq * 4;
        *(float4*)dst = v;
    }
    __syncthreads();
    float accs = 0.f;
    {
        const float* sw2q = sw2 + qu * 64;
        const float* ra = sSa + (q * 8 + pi) * 68;
        const float* rb = sSb + (q * 8 + pj) * 68;
        #pragma unroll 16
        for (int kk = 0; kk < 64; ++kk) {
            float h = fmaxf(ra[kk] + rb[kk], 0.f);
            accs = fmaf(h, sw2q[kk], accs);
        }
    }

    // ---------------- classifier (fp64), K=128 per quarter ----------------
    double lg[10];
    #pragma unroll
    for (int c = 0; c < 10; ++c) lg[c] = 0.0;
    const double* wq = cw2d + qu * 1280;

    for (int c4 = 0; c4 < 4; ++c4) {
        __syncthreads();   // prior reads of sA/sB (or sSa/sSb) done
        #pragma unroll
        for (int u = 0; u < 4; ++u) {
            int idx = u * 256 + t;
            int kq  = idx & 15;
            int row = (idx >> 4) & 7;
            int qq  = (idx >> 7) & 3;
            int arr = idx >> 9;
            const double* src = arr ? (cb_d + (j0 + row) * 512) : (ca_d + (i0 + row) * 512);
            double2 v = *(const double2*)(src + qq * 128 + c4 * 32 + kq * 2);
            double* dst = (arr ? sB : sA) + (qq * 8 + row) * 34 + kq * 2;
            *(double2*)dst = v;
        }
        __syncthreads();
        const double* ra = sA + (q * 8 + pi) * 34;
        const double* rb = sB + (q * 8 + pj) * 34;
        const double* wc = wq + c4 * 320;
        #pragma unroll 8
        for (int kk = 0; kk < 32; ++kk) {
            double h = fmax(ra[kk] + rb[kk], 0.0);
            const double* w = wc + kk * 10;
            #pragma unroll
            for (int c = 0; c < 10; ++c) lg[c] = fma(h, w[c], lg[c]);
        }
    }

    // ---------------- combine via LDS ----------------
    __syncthreads();
    if (q > 0) {
        double* dst = lgbuf + ((q - 1) * 64 + l) * 10;
        #pragma unroll
        for (int c = 0; c < 10; ++c) dst[c] = lg[c];
        stbuf[(q - 1) * 64 + l] = accs;
    }
    __syncthreads();
    if (q == 0) {
        #pragma unroll
        for (int w = 0; w < 3; ++w) {
            const double* srcb = lgbuf + (w * 64 + l) * 10;
            #pragma unroll
            for (int c = 0; c < 10; ++c) lg[c] += srcb[c];
        }
        float st = accs + stbuf[l] + stbuf[64 + l] + stbuf[128 + l] + sb2[0];

        #pragma unroll
        for (int c = 0; c < 10; ++c) lg[c] += (double)cb2[c];
        double mx = lg[0]; int am2 = 0;
        #pragma unroll
        for (int c = 1; c < 10; ++c) {
            if (lg[c] > mx) { mx = lg[c]; am2 = c; }   // first-max == np.argmax
        }
        float tf[10]; float s = 0.f;
        #pragma unroll
        for (int c = 0; c < 10; ++c) { tf[c] = (float)(lg[c] - mx); s += __expf(tf[c]); }
        float ls = __logf(s);

        if (j > i) {
            const int p = i * 511 - (i * (i - 1)) / 2 + (j - i - 1);
            float* tp = out + TYPES_OFF + p * 10;
            #pragma unroll
            for (int c = 0; c < 10; ++c) tp[c] = tf[c] - ls;
            out[ARGMAX_OFF + p] = (float)am2;
            out[STRENGTH_OFF + p] = 1.0f / (1.0f + __expf(-st));
        }
    }
}

extern "C" void kernel_launch(void* const* d_in, const int* in_sizes, int n_in,
                              void* d_out, int out_size, void* d_ws, size_t ws_size,
                              hipStream_t stream) {
    const float* F   = (const float*)d_in[0];
    const float* cw1 = (const float*)d_in[1];
    const float* cb1 = (const float*)d_in[2];
    const float* cw2 = (const float*)d_in[3];
    const float* cb2 = (const float*)d_in[4];
    const float* sw1 = (const float*)d_in[5];
    const float* sb1 = (const float*)d_in[6];
    const float* sw2 = (const float*)d_in[7];
    const float* sb2 = (const float*)d_in[8];
    float* out = (float*)d_out;

    char* ws = (char*)d_ws;
    double* ca_d = (double*)(ws);
    double* cb_d = (double*)(ws + 2097152);
    float*  sa_f = (float*)(ws + 4194304);
    float*  sb_f = (float*)(ws + 4718592);
    double* cw2d = (double*)(ws + 5242880);

    hipLaunchKernelGGL(init_ws_kernel, dim3(1024), dim3(256), 0, stream,
                       cb1, sb1, cw2, ca_d, cb_d, sa_f, sb_f, cw2d);
    hipLaunchKernelGGL(proj_kernel, dim3(384), dim3(256), 0, stream,
                       F, cw1, sw1, ca_d, cb_d, sa_f, sb_f);
    hipLaunchKernelGGL(pair_kernel, dim3(2080), dim3(256), 0, stream,
                       ca_d, cb_d, sa_f, sb_f, cw2d, cb2, sw2, sb2, out);
}